// Round 1
// baseline (31.664 us; speedup 1.0000x reference)
//
#include <hip/hip_runtime.h>

#define TPB 256
#define NDIM 8

__global__ __launch_bounds__(TPB) void vegas_map_kernel(
    const float* __restrict__ u,      // [n, 8]
    const float* __restrict__ grid,   // [8, gcols]
    float* __restrict__ x_out,        // [n, 8]
    float* __restrict__ lj_out,       // [n]
    int n, int gcols)
{
    extern __shared__ float lds_grid[];   // 8 * gcols floats
    const int ninc = gcols - 1;
    const int gtot = NDIM * gcols;

    // Stage the whole grid table into LDS (32 KB for gcols=1001).
    for (int t = threadIdx.x; t < gtot; t += TPB)
        lds_grid[t] = grid[t];
    __syncthreads();

    const float fninc = (float)ninc;
    const float4* __restrict__ u4 = (const float4*)u;
    float4* __restrict__ x4 = (float4*)x_out;

    const int stride = gridDim.x * TPB;
    for (int p = blockIdx.x * TPB + threadIdx.x; p < n; p += stride) {
        float4 ua = u4[2 * p];
        float4 ub = u4[2 * p + 1];
        float uv[NDIM] = {ua.x, ua.y, ua.z, ua.w, ub.x, ub.y, ub.z, ub.w};
        float xv[NDIM];
        float prod = 1.0f;

        #pragma unroll
        for (int d = 0; d < NDIM; ++d) {
            float un = uv[d] * fninc;
            int   iu = (int)un;            // trunc == floor (un >= 0)
            float du = un - (float)iu;
            bool  in = iu < ninc;
            int   iuc = in ? iu : (ninc - 1);
            const float* row = lds_grid + d * gcols;
            float g0 = row[iuc];
            float g1 = row[iuc + 1];
            float h  = g1 - g0;            // == inc[d][iuc] bit-exactly
            xv[d] = in ? (g0 + h * du) : row[ninc];
            prod *= h * fninc;             // fac; mask case identical (h == inc_last)
        }

        float4 oa = {xv[0], xv[1], xv[2], xv[3]};
        float4 ob = {xv[4], xv[5], xv[6], xv[7]};
        x4[2 * p]     = oa;
        x4[2 * p + 1] = ob;
        lj_out[p] = logf(prod);            // sum of logs == log of product
    }
}

extern "C" void kernel_launch(void* const* d_in, const int* in_sizes, int n_in,
                              void* d_out, int out_size, void* d_ws, size_t ws_size,
                              hipStream_t stream) {
    const float* u    = (const float*)d_in[0];   // [N, 8]
    const float* grid = (const float*)d_in[1];   // [8, ninc+1]
    // d_in[2] = inc (recomputed from grid diffs on the fly), d_in[3] = ninc scalar (unused; derived)
    const int n     = in_sizes[0] / NDIM;
    const int gcols = in_sizes[1] / NDIM;        // ninc + 1

    float* x_out  = (float*)d_out;
    float* lj_out = (float*)d_out + (size_t)n * NDIM;

    int blocks = (n + TPB - 1) / TPB;
    if (blocks > 2048) blocks = 2048;
    size_t lds_bytes = (size_t)NDIM * gcols * sizeof(float);

    vegas_map_kernel<<<blocks, TPB, lds_bytes, stream>>>(u, grid, x_out, lj_out, n, gcols);
}